// Round 1
// baseline (293.468 us; speedup 1.0000x reference)
//
#include <hip/hip_runtime.h>

typedef __bf16 bf16;
typedef __bf16 bf16x4 __attribute__((ext_vector_type(4)));
typedef __bf16 bf16x8 __attribute__((ext_vector_type(8)));
typedef float f32x4 __attribute__((ext_vector_type(4)));

__device__ __forceinline__ f32x4 mfma16(bf16x8 a, bf16x8 b, f32x4 c) {
  return __builtin_amdgcn_mfma_f32_16x16x32_bf16(a, b, c, 0, 0, 0);
}

// ---------------------------------------------------------------------------
// RMSNorm: one wave per 256-elem row. Handles both t and f in one grid.
// ---------------------------------------------------------------------------
__global__ __launch_bounds__(256)
void rms_kernel(const float* __restrict__ t, const float* __restrict__ f,
                const float* __restrict__ w, bf16* __restrict__ tn,
                bf16* __restrict__ fn, int rows_t)
{
  int wave = threadIdx.x >> 6;
  int lane = threadIdx.x & 63;
  int row = blockIdx.x * 4 + wave;
  const float* src;
  bf16* dst;
  if (row < rows_t) {
    src = t + (size_t)row * 256;
    dst = tn + (size_t)row * 256;
  } else {
    int r2 = row - rows_t;
    src = f + (size_t)r2 * 256;
    dst = fn + (size_t)r2 * 256;
  }
  float4 v = reinterpret_cast<const float4*>(src)[lane];
  float ss = v.x * v.x + v.y * v.y + v.z * v.z + v.w * v.w;
  #pragma unroll
  for (int m = 1; m < 64; m <<= 1) ss += __shfl_xor(ss, m);
  float nrm = rsqrtf(ss * (1.0f / 256.0f) + 1e-5f);
  float4 wv = reinterpret_cast<const float4*>(w)[lane];
  bf16x4 o;
  o[0] = (bf16)(v.x * nrm * wv.x);
  o[1] = (bf16)(v.y * nrm * wv.y);
  o[2] = (bf16)(v.z * nrm * wv.z);
  o[3] = (bf16)(v.w * nrm * wv.w);
  *reinterpret_cast<bf16x4*>(dst + lane * 4) = o;
}

// ---------------------------------------------------------------------------
// Weight transpose + fp32->bf16: dst[n*256 + k] = (bf16) src[k*N + n]
// K is always 256 for this problem.
// ---------------------------------------------------------------------------
__global__ __launch_bounds__(256)
void transpose_w(const float* __restrict__ src, bf16* __restrict__ dst, int N)
{
  int idx = blockIdx.x * 256 + threadIdx.x;   // idx = n*256 + k
  int k = idx & 255;
  int n = idx >> 8;
  dst[idx] = (bf16)src[(size_t)k * N + n];
}

// ---------------------------------------------------------------------------
// GEMM: out[M=8192, N] = A[8192,256](bf16) @ W[256,N] + bias
// Wt is W transposed (N x 256, bf16) so B-fragments are contiguous loads.
// Block tile 64x64, 4 waves in 2x2, each wave 32x32 via 2x2 MFMA frags.
// MODE 0: write Q layout  [b*4+h][t][d]          (o0)
// MODE 1: write K layout  [b*4+h][f][d]          (o0, cols 0..255)
//         write Vt layout [b*4+h][d][f]          (o1, cols 256..511)
// MODE 2: fp32 out = acc + bias + resid(bf16)    (outf)
// ---------------------------------------------------------------------------
template<int MODE>
__global__ __launch_bounds__(256)
void gemm_k256(const bf16* __restrict__ A, const bf16* __restrict__ Wt,
               const float* __restrict__ bias, bf16* __restrict__ o0,
               bf16* __restrict__ o1, const bf16* __restrict__ resid,
               float* __restrict__ outf, int N)
{
  int wv = threadIdx.x >> 6;
  int lane = threadIdx.x & 63;
  int lr = lane & 15;
  int lk = (lane >> 4) * 8;
  int wm = wv >> 1, wn = wv & 1;
  int nb = N >> 6;
  int bm = blockIdx.x / nb;
  int bn = blockIdx.x - bm * nb;
  int row0 = bm * 64 + wm * 32;
  int col0 = bn * 64 + wn * 32;
  const bf16* Ap = A + (size_t)row0 * 256;
  const bf16* Wp = Wt + (size_t)col0 * 256;

  f32x4 acc[2][2] = {};
  #pragma unroll
  for (int k0 = 0; k0 < 256; k0 += 32) {
    bf16x8 a[2], b[2];
    #pragma unroll
    for (int mi = 0; mi < 2; mi++)
      a[mi] = *reinterpret_cast<const bf16x8*>(Ap + (size_t)(mi * 16 + lr) * 256 + k0 + lk);
    #pragma unroll
    for (int ni = 0; ni < 2; ni++)
      b[ni] = *reinterpret_cast<const bf16x8*>(Wp + (size_t)(ni * 16 + lr) * 256 + k0 + lk);
    #pragma unroll
    for (int mi = 0; mi < 2; mi++)
      #pragma unroll
      for (int ni = 0; ni < 2; ni++)
        acc[mi][ni] = mfma16(a[mi], b[ni], acc[mi][ni]);
  }

  int rb = (lane >> 4) * 4;
  #pragma unroll
  for (int mi = 0; mi < 2; mi++) {
    #pragma unroll
    for (int ni = 0; ni < 2; ni++) {
      int col = col0 + ni * 16 + lr;
      float bv = bias[col];
      #pragma unroll
      for (int r = 0; r < 4; r++) {
        int row = row0 + mi * 16 + rb + r;
        float val = acc[mi][ni][r] + bv;
        if (MODE == 0) {
          int b_ = row >> 12, tt = row & 4095;
          int h = col >> 6, d = col & 63;
          o0[(((size_t)(b_ * 4 + h)) * 4096 + tt) * 64 + d] = (bf16)val;
        } else if (MODE == 1) {
          int b_ = row >> 12, ff = row & 4095;
          if (col < 256) {
            int h = col >> 6, d = col & 63;
            o0[(((size_t)(b_ * 4 + h)) * 4096 + ff) * 64 + d] = (bf16)val;
          } else {
            int c = col - 256;
            int h = c >> 6, d = c & 63;
            o1[(((size_t)(b_ * 4 + h)) * 64 + d) * 4096 + ff] = (bf16)val;
          }
        } else {
          size_t idx = (size_t)row * 256 + col;
          outf[idx] = val + (float)resid[idx];
        }
      }
    }
  }
}

// ---------------------------------------------------------------------------
// Flash attention: grid = (B*H) * (Nt/64) blocks, 4 independent waves each.
// Wave owns 16 Q rows; loops over Nf in 64-wide K/V tiles.
// Q layout [bh][t][d], K layout [bh][f][d], Vt layout [bh][d][f] (all bf16).
// Online softmax; P goes through padded LDS to re-shape for the PV MFMA.
// ---------------------------------------------------------------------------
__global__ __launch_bounds__(256)
void attn_kernel(const bf16* __restrict__ Q, const bf16* __restrict__ K,
                 const bf16* __restrict__ Vt, bf16* __restrict__ AO)
{
  int bh = blockIdx.x >> 6;        // 0..7  (b*4+h)
  int tb = blockIdx.x & 63;        // t-tile
  int wv = threadIdx.x >> 6;
  int lane = threadIdx.x & 63;
  int lr = lane & 15;
  int lg = lane >> 4;
  int lk = lg * 8;
  int t0 = tb * 64 + wv * 16;

  const bf16* Qb = Q + ((size_t)bh * 4096 + t0) * 64;
  const bf16* Kb = K + (size_t)bh * 4096 * 64;
  const bf16* Vb = Vt + (size_t)bh * 64 * 4096;

  bf16x8 qf[2];
  qf[0] = *reinterpret_cast<const bf16x8*>(Qb + (size_t)lr * 64 + lk);
  qf[1] = *reinterpret_cast<const bf16x8*>(Qb + (size_t)lr * 64 + 32 + lk);

  f32x4 o[4] = {};
  float mrow[4] = {-3.0e38f, -3.0e38f, -3.0e38f, -3.0e38f};
  float lrow[4] = {0.f, 0.f, 0.f, 0.f};

  __shared__ bf16 plds[4][16][72];   // per-wave P tile, stride 72 kills conflicts
  bf16* myp = &plds[wv][0][0];
  const float scale = 0.125f;        // 1/sqrt(64)

  for (int f0 = 0; f0 < 4096; f0 += 64) {
    // S = Q K^T for this 16x64 tile
    f32x4 s[4] = {};
    #pragma unroll
    for (int fi = 0; fi < 4; fi++) {
      const bf16* kp = Kb + (size_t)(f0 + fi * 16 + lr) * 64 + lk;
      bf16x8 k0 = *reinterpret_cast<const bf16x8*>(kp);
      bf16x8 k1 = *reinterpret_cast<const bf16x8*>(kp + 32);
      s[fi] = mfma16(qf[0], k0, s[fi]);
      s[fi] = mfma16(qf[1], k1, s[fi]);
    }
    // online softmax (rows live in 16-lane groups; shfl_xor 1,2,4,8)
    float alpha[4];
    #pragma unroll
    for (int r = 0; r < 4; r++) {
      float tm = fmaxf(fmaxf(s[0][r], s[1][r]), fmaxf(s[2][r], s[3][r])) * 1.0f;
      // scale S first
      #pragma unroll
      for (int fi = 0; fi < 4; fi++) s[fi][r] *= scale;
      tm *= scale;
      #pragma unroll
      for (int m = 1; m < 16; m <<= 1) tm = fmaxf(tm, __shfl_xor(tm, m));
      float mn = fmaxf(mrow[r], tm);
      alpha[r] = __expf(mrow[r] - mn);
      mrow[r] = mn;
      float ps = 0.f;
      #pragma unroll
      for (int fi = 0; fi < 4; fi++) {
        float p = __expf(s[fi][r] - mn);
        s[fi][r] = p;
        ps += p;
      }
      #pragma unroll
      for (int m = 1; m < 16; m <<= 1) ps += __shfl_xor(ps, m);
      lrow[r] = lrow[r] * alpha[r] + ps;
    }
    #pragma unroll
    for (int df = 0; df < 4; df++)
      #pragma unroll
      for (int r = 0; r < 4; r++) o[df][r] *= alpha[r];

    // P -> LDS (bf16), re-read as A-fragments
    #pragma unroll
    for (int fi = 0; fi < 4; fi++)
      #pragma unroll
      for (int r = 0; r < 4; r++)
        myp[(lg * 4 + r) * 72 + fi * 16 + lr] = (bf16)s[fi][r];

    bf16x8 pa0 = *reinterpret_cast<const bf16x8*>(myp + lr * 72 + lk);
    bf16x8 pa1 = *reinterpret_cast<const bf16x8*>(myp + lr * 72 + 32 + lk);

    #pragma unroll
    for (int df = 0; df < 4; df++) {
      const bf16* vp = Vb + (size_t)(df * 16 + lr) * 4096 + f0 + lk;
      bf16x8 v0 = *reinterpret_cast<const bf16x8*>(vp);
      bf16x8 v1 = *reinterpret_cast<const bf16x8*>(vp + 32);
      o[df] = mfma16(pa0, v0, o[df]);
      o[df] = mfma16(pa1, v1, o[df]);
    }
  }

  // epilogue: normalize and write AO[b][t][h*64+d]
  int b_ = bh >> 2, h = bh & 3;
  #pragma unroll
  for (int df = 0; df < 4; df++) {
    #pragma unroll
    for (int r = 0; r < 4; r++) {
      int row = t0 + lg * 4 + r;
      int d = df * 16 + lr;
      float val = o[df][r] / lrow[r];
      AO[((size_t)b_ * 4096 + row) * 256 + h * 64 + d] = (bf16)val;
    }
  }
}

// ---------------------------------------------------------------------------
extern "C" void kernel_launch(void* const* d_in, const int* in_sizes, int n_in,
                              void* d_out, int out_size, void* d_ws, size_t ws_size,
                              hipStream_t stream) {
  const float* t   = (const float*)d_in[0];
  const float* f   = (const float*)d_in[1];
  const float* nw  = (const float*)d_in[2];
  const float* wq  = (const float*)d_in[3];
  const float* bq  = (const float*)d_in[4];
  const float* wkv = (const float*)d_in[5];
  const float* bkv = (const float*)d_in[6];
  const float* wp  = (const float*)d_in[7];
  const float* bp  = (const float*)d_in[8];
  float* out = (float*)d_out;

  bf16* ws = (bf16*)d_ws;
  const size_t NTOK = 2097152;        // 2*4096*256
  bf16* tn   = ws;
  bf16* fn   = ws + NTOK;
  bf16* q    = ws + 2 * NTOK;
  bf16* k    = ws + 3 * NTOK;
  bf16* vt   = ws + 4 * NTOK;
  bf16* ao   = ws + 5 * NTOK;
  bf16* wqT  = ws + 6 * NTOK;
  bf16* wkvT = wqT + 65536;
  bf16* wpT  = wkvT + 131072;

  transpose_w<<<256, 256, 0, stream>>>(wq, wqT, 256);
  transpose_w<<<512, 256, 0, stream>>>(wkv, wkvT, 512);
  transpose_w<<<256, 256, 0, stream>>>(wp, wpT, 256);
  rms_kernel<<<4096, 256, 0, stream>>>(t, f, nw, tn, fn, 8192);
  gemm_k256<0><<<512, 256, 0, stream>>>(tn, wqT, bq, q, nullptr, nullptr, nullptr, 256);
  gemm_k256<1><<<1024, 256, 0, stream>>>(fn, wkvT, bkv, k, vt, nullptr, nullptr, 512);
  attn_kernel<<<512, 256, 0, stream>>>(q, k, vt, ao);
  gemm_k256<2><<<512, 256, 0, stream>>>(ao, wpT, bp, nullptr, nullptr, tn, out, 256);
}